// Round 3
// baseline (428.476 us; speedup 1.0000x reference)
//
#include <hip/hip_runtime.h>
#include <hip/hip_bf16.h>

// Shapes (fixed by the reference)
#define QN 64
#define SQ 32
#define CN 256
#define SC 256
#define HD 768
#define DD 128

typedef __attribute__((ext_vector_type(8))) short short8;   // 8 bf16 = 4 VGPR
typedef __attribute__((ext_vector_type(4))) float f32x4;    // MFMA acc

// ---- bf16 pack helpers (RNE) ----
static __device__ __forceinline__ unsigned short f2bf(float x) {
  unsigned u = __float_as_uint(x);
  unsigned r = 0x7FFFu + ((u >> 16) & 1u);
  return (unsigned short)((u + r) >> 16);
}
static __device__ __forceinline__ unsigned pack2(float a, float b) {
  return (unsigned)f2bf(a) | ((unsigned)f2bf(b) << 16);
}

// ---------------------------------------------------------------------------
// Prep (fused): blocks [0,128): Wt[d][k] = bf16(W[k][d]) column convert.
//               blocks [128,448): pooled l2norm rows (64 q + 256 c);
//                                 q-blocks also zero qcolP pad row 31.
// ---------------------------------------------------------------------------
__global__ __launch_bounds__(256) void prep_kernel(
    const float* __restrict__ W,
    const float* __restrict__ qh, const int* __restrict__ qm,
    const float* __restrict__ ch, const int* __restrict__ cm,
    unsigned short* __restrict__ Wt,
    float* __restrict__ outq, float* __restrict__ outc,
    unsigned short* __restrict__ qcolP) {
  __shared__ float red[4];
  int bid = blockIdx.x, tid = threadIdx.x;

  if (bid < DD) {  // W transpose-convert
    for (int k = tid; k < HD; k += 256)
      Wt[bid * HD + k] = f2bf(W[(size_t)k * DD + bid]);
    return;
  }

  int row = bid - DD;
  const float* src;
  float* dst;
  float m;
  if (row < QN) {
    src = qh + (size_t)row * SQ * HD;
    m = (float)qm[row * SQ];
    dst = outq + (size_t)row * HD;
  } else {
    int b = row - QN;
    src = ch + (size_t)b * SC * HD;
    m = (float)cm[b * SC];
    dst = outc + (size_t)b * HD;
  }
  float ss = 0.f;
  for (int k = tid; k < HD; k += 256) {
    float v = src[k] * m;
    ss += v * v;
  }
  int lane = tid & 63, wv = tid >> 6;
  for (int off = 32; off; off >>= 1) ss += __shfl_xor(ss, off);
  if (lane == 0) red[wv] = ss;
  __syncthreads();
  float tot = red[0] + red[1] + red[2] + red[3];
  float inv = 1.f / fmaxf(sqrtf(tot), 1e-12f);
  for (int k = tid; k < HD; k += 256) dst[k] = src[k] * m * inv;
  // zero pad row (i = 31) of qcolP for this q
  if (row < QN && tid < 64)
    ((unsigned*)(qcolP + ((size_t)row * 32 + 31) * DD))[tid] = 0u;
}

// ---------------------------------------------------------------------------
// Projection GEMM (MFMA, fused q+c): col = l2norm(bf16(h*mask) @ Wt^T + bias)
// Blocks [0,1020): c batches.  Blocks [1020,1051): q batches.
// Tile: 64 tokens x 128 d, K=768 in BK=64 steps, 256 thr = 4 waves.
// Software-pipelined: next k-step's global loads prefetched during MFMA.
// LDS XOR swizzle on 16B chunks: phys_chunk = kc ^ (row & 7).
// ---------------------------------------------------------------------------
union ProjLDS {
  struct { unsigned short a[64 * 64]; unsigned short b[128 * 64]; } s;
  float c[64 * 132];
};

__global__ __launch_bounds__(256) void proj_kernel(
    const float* __restrict__ q_hidden, const float* __restrict__ c_hidden,
    const int* __restrict__ q_mask, const int* __restrict__ c_mask,
    const unsigned short* __restrict__ Wt, const float* __restrict__ bias,
    unsigned short* __restrict__ qcol, unsigned short* __restrict__ ccol) {
  __shared__ ProjLDS u;
  int bx = blockIdx.x;
  int isQ = (bx >= 1020) ? 1 : 0;
  int base = isQ ? (bx - 1020) : bx;
  const float* hidden = isQ ? q_hidden : c_hidden;
  const int* mask = isQ ? q_mask : c_mask;
  int S = isQ ? SQ : SC;
  int T = S - 1;
  int OUTS = isQ ? 32 : 256;
  unsigned short* out = isQ ? qcol : ccol;

  int tid = threadIdx.x, lane = tid & 63, w = tid >> 6;
  int lm = lane & 15, lq = lane >> 4;
  int wm = w & 1, wn = w >> 1;

  // A staging role: 4 threads per token row, 16 consecutive f32 each
  int ar = tid >> 2, aseg = tid & 3;
  int ag = base * 64 + ar;
  int ab = ag / T, at = ag - ab * T;
  const float* hrow = hidden + ((size_t)ab * S + at + 1) * HD + aseg * 16;
  float am = (float)mask[ab * S + at + 1];
  // B staging role: 2 threads per d row, 32 bf16 each
  int bd = tid >> 1, bh = tid & 1;
  const unsigned short* wrow = Wt + (size_t)bd * HD + bh * 32;

  f32x4 acc[2][4];
#pragma unroll
  for (int i = 0; i < 2; ++i)
#pragma unroll
    for (int j = 0; j < 4; ++j) acc[i][j] = (f32x4){0.f, 0.f, 0.f, 0.f};

  // initial prefetch (k0 = 0)
  float4 va[4];
  uint4 vb[4];
#pragma unroll
  for (int j = 0; j < 4; ++j) va[j] = ((const float4*)hrow)[j];
#pragma unroll
  for (int j = 0; j < 4; ++j) vb[j] = ((const uint4*)wrow)[j];

  for (int k0 = 0; k0 < HD; k0 += 64) {
    __syncthreads();
    // ---- write staged tile to LDS ----
    {
      unsigned p[8];
      p[0] = pack2(va[0].x * am, va[0].y * am); p[1] = pack2(va[0].z * am, va[0].w * am);
      p[2] = pack2(va[1].x * am, va[1].y * am); p[3] = pack2(va[1].z * am, va[1].w * am);
      p[4] = pack2(va[2].x * am, va[2].y * am); p[5] = pack2(va[2].z * am, va[2].w * am);
      p[6] = pack2(va[3].x * am, va[3].y * am); p[7] = pack2(va[3].z * am, va[3].w * am);
      int kc0 = aseg * 2;
      int pk0 = kc0 ^ (ar & 7), pk1 = (kc0 + 1) ^ (ar & 7);
      *(uint4*)&u.s.a[(ar * 8 + pk0) * 8] = *(uint4*)&p[0];
      *(uint4*)&u.s.a[(ar * 8 + pk1) * 8] = *(uint4*)&p[4];
#pragma unroll
      for (int j = 0; j < 4; ++j) {
        int kc = bh * 4 + j;
        int pk = kc ^ (bd & 7);
        *(uint4*)&u.s.b[(bd * 8 + pk) * 8] = vb[j];
      }
    }
    __syncthreads();
    // ---- prefetch next k-step ----
    if (k0 + 64 < HD) {
      const float4* hp = (const float4*)(hrow + k0 + 64);
      const uint4* wp = (const uint4*)(wrow + k0 + 64);
#pragma unroll
      for (int j = 0; j < 4; ++j) va[j] = hp[j];
#pragma unroll
      for (int j = 0; j < 4; ++j) vb[j] = wp[j];
    }
    // ---- MFMA: wave tile 32 tok x 64 d ----
#pragma unroll
    for (int kf = 0; kf < 2; ++kf) {
      short8 a2[2], b4[4];
#pragma unroll
      for (int mt = 0; mt < 2; ++mt) {
        int row = (wm * 2 + mt) * 16 + lm;
        int kc = kf * 4 + lq;
        a2[mt] = *(const short8*)&u.s.a[(row * 8 + (kc ^ (row & 7))) * 8];
      }
#pragma unroll
      for (int nt = 0; nt < 4; ++nt) {
        int row = (wn * 4 + nt) * 16 + lm;
        int kc = kf * 4 + lq;
        b4[nt] = *(const short8*)&u.s.b[(row * 8 + (kc ^ (row & 7))) * 8];
      }
#pragma unroll
      for (int mt = 0; mt < 2; ++mt)
#pragma unroll
        for (int nt = 0; nt < 4; ++nt)
          acc[mt][nt] = __builtin_amdgcn_mfma_f32_16x16x32_bf16(a2[mt], b4[nt], acc[mt][nt], 0, 0, 0);
    }
  }

  // ---- epilogue: C tile -> LDS, bias + l2norm, bf16 store ----
  __syncthreads();
#pragma unroll
  for (int mt = 0; mt < 2; ++mt)
#pragma unroll
    for (int nt = 0; nt < 4; ++nt)
#pragma unroll
      for (int r = 0; r < 4; ++r) {
        int row = (wm * 2 + mt) * 16 + lq * 4 + r;
        int col = (wn * 4 + nt) * 16 + lm;
        u.c[row * 132 + col] = acc[mt][nt][r];
      }
  __syncthreads();

  int r2 = tid >> 2, seg2 = tid & 3;
  float v[32];
  float ss = 0.f;
#pragma unroll
  for (int j = 0; j < 8; ++j) {
    float4 cv = *(const float4*)&u.c[r2 * 132 + seg2 * 32 + j * 4];
    float4 bv = *(const float4*)&bias[seg2 * 32 + j * 4];
    v[4 * j + 0] = cv.x + bv.x; v[4 * j + 1] = cv.y + bv.y;
    v[4 * j + 2] = cv.z + bv.z; v[4 * j + 3] = cv.w + bv.w;
#pragma unroll
    for (int e = 0; e < 4; ++e) ss += v[4 * j + e] * v[4 * j + e];
  }
  ss += __shfl_xor(ss, 1);
  ss += __shfl_xor(ss, 2);
  float inv = 1.f / fmaxf(sqrtf(ss), 1e-12f);

  unsigned pk[16];
#pragma unroll
  for (int j = 0; j < 16; ++j) pk[j] = pack2(v[2 * j] * inv, v[2 * j + 1] * inv);

  int g = base * 64 + r2;
  int b = g / T, tt = g - b * T;
  unsigned short* dst = out + ((size_t)b * OUTS + tt) * DD + seg2 * 32;
  uint4* d4 = (uint4*)dst;
  d4[0] = *(uint4*)&pk[0];  d4[1] = *(uint4*)&pk[4];
  d4[2] = *(uint4*)&pk[8];  d4[3] = *(uint4*)&pk[12];
  if (!isQ && tt == 254) {  // duplicate token 254 into pad row 255
    uint4* d5 = (uint4*)(dst + DD);
    d5[0] = *(uint4*)&pk[0];  d5[1] = *(uint4*)&pk[4];
    d5[2] = *(uint4*)&pk[8];  d5[3] = *(uint4*)&pk[12];
  }
}

// ---------------------------------------------------------------------------
// Sim (MFMA): sim[q,c] = (sum_i max_j qcol[q,i]·ccol[c,j]) / denom[q]
// Grid (64 c-tiles, 8 q-tiles), 128 thr = 2 waves, 2 blocks/CU (64 KB LDS).
// Each wave holds 4 q's B-fragments in regs (8 m-tiles); c-tile in LDS is the
// A operand, so D rows = c-tokens j: max-over-j reduces in-lane (r) + lq shfl.
// ---------------------------------------------------------------------------
__global__ __launch_bounds__(128, 1) void sim_kernel(
    const unsigned short* __restrict__ qcolP,  // [64][32][128], row 31 zero
    const unsigned short* __restrict__ ccol,   // [256][256][128], row 255 dup
    const int* __restrict__ qmask,
    float* __restrict__ sim) {
  __shared__ unsigned short cbuf[256 * 128];   // 64 KB
  int tid = threadIdx.x, lane = tid & 63, w = tid >> 6;
  int lm = lane & 15, lq = lane >> 4;
  int qb = blockIdx.y * 8 + w * 4;  // 4 q per wave
  int c0 = blockIdx.x * 4;

  // B fragments (q side): af[q2][it][kf]
  short8 af[4][2][4];
#pragma unroll
  for (int q2 = 0; q2 < 4; ++q2)
#pragma unroll
    for (int it = 0; it < 2; ++it)
#pragma unroll
      for (int kf = 0; kf < 4; ++kf)
        af[q2][it][kf] = *(const short8*)(qcolP +
            (((size_t)(qb + q2) * 32 + it * 16 + lm) * DD + kf * 32 + lq * 8));

  float dinv[4];
#pragma unroll
  for (int q2 = 0; q2 < 4; ++q2) {
    float v = (lane >= 1 && lane < 32) ? (float)qmask[(qb + q2) * SQ + lane] : 0.f;
    for (int off = 1; off < 64; off <<= 1) v += __shfl_xor(v, off);
    dinv[q2] = 1.f / v;
  }

  for (int cc = 0; cc < 4; ++cc) {
    int c = c0 + cc;
    __syncthreads();
    // ---- stage c-tile (256 x 128 bf16 = 64 KB), XOR-swizzled chunks ----
    const uint4* src = (const uint4*)(ccol + (size_t)c * SC * DD);
#pragma unroll
    for (int g4 = 0; g4 < 4; ++g4) {
      uint4 tmp[8];
#pragma unroll
      for (int it = 0; it < 8; ++it) tmp[it] = src[(g4 * 8 + it) * 128 + tid];
#pragma unroll
      for (int it = 0; it < 8; ++it) {
        int idx = (g4 * 8 + it) * 128 + tid;
        int row = idx >> 4, kc = idx & 15;
        int pkc = (kc & 8) | ((kc & 7) ^ (row & 7));
        *(uint4*)&cbuf[(row * 16 + pkc) * 8] = tmp[it];
      }
    }
    __syncthreads();

    float rmax[4][2];
#pragma unroll
    for (int q2 = 0; q2 < 4; ++q2) { rmax[q2][0] = -__builtin_inff(); rmax[q2][1] = -__builtin_inff(); }

    for (int jt = 0; jt < 16; ++jt) {
      short8 cf[4];  // A operand: c rows jt*16+lm
#pragma unroll
      for (int kf = 0; kf < 4; ++kf) {
        int row = jt * 16 + lm;
        int kc = kf * 4 + lq;
        int pkc = (kc & 8) | ((kc & 7) ^ (row & 7));
        cf[kf] = *(const short8*)&cbuf[(row * 16 + pkc) * 8];
      }
#pragma unroll
      for (int q2 = 0; q2 < 4; ++q2)
#pragma unroll
        for (int it = 0; it < 2; ++it) {
          f32x4 acc = (f32x4){0.f, 0.f, 0.f, 0.f};
#pragma unroll
          for (int kf = 0; kf < 4; ++kf)
            acc = __builtin_amdgcn_mfma_f32_16x16x32_bf16(cf[kf], af[q2][it][kf], acc, 0, 0, 0);
          float loc = fmaxf(fmaxf(acc[0], acc[1]), fmaxf(acc[2], acc[3]));
          rmax[q2][it] = fmaxf(rmax[q2][it], loc);
        }
    }

#pragma unroll
    for (int q2 = 0; q2 < 4; ++q2) {
      float m0 = rmax[q2][0], m1 = rmax[q2][1];
      m0 = fmaxf(m0, __shfl_xor(m0, 16)); m0 = fmaxf(m0, __shfl_xor(m0, 32));
      m1 = fmaxf(m1, __shfl_xor(m1, 16)); m1 = fmaxf(m1, __shfl_xor(m1, 32));
      // q-row i = lm (+16 for it=1); pad row 31 = (it=1, lm=15) excluded
      float s = m0 + ((lm == 15) ? 0.f : m1);
      s += __shfl_xor(s, 1); s += __shfl_xor(s, 2);
      s += __shfl_xor(s, 4); s += __shfl_xor(s, 8);
      if (lane == 0) sim[(qb + q2) * CN + c] = s * dinv[q2];
    }
  }
}

// ---------------------------------------------------------------------------
extern "C" void kernel_launch(void* const* d_in, const int* in_sizes, int n_in,
                              void* d_out, int out_size, void* d_ws, size_t ws_size,
                              hipStream_t stream) {
  const float* q_hidden = (const float*)d_in[0];
  const float* c_hidden = (const float*)d_in[1];
  const float* W = (const float*)d_in[2];
  const float* bias = (const float*)d_in[3];
  const int* q_mask = (const int*)d_in[4];
  const int* c_mask = (const int*)d_in[5];

  float* out = (float*)d_out;
  float* sim = out;                      // 64*256
  float* q_pooled = out + QN * CN;       // 64*768
  float* c_pooled = q_pooled + QN * HD;  // 256*768

  unsigned short* Wt    = (unsigned short*)d_ws;                        // 192 KB
  unsigned short* qcolP = (unsigned short*)((char*)d_ws + (256 << 10)); // 512 KB
  unsigned short* ccol  = (unsigned short*)((char*)d_ws + (1 << 20));   // 16 MB

  prep_kernel<<<DD + QN + CN, 256, 0, stream>>>(W, q_hidden, q_mask, c_hidden, c_mask,
                                                Wt, q_pooled, c_pooled, qcolP);
  proj_kernel<<<1051, 256, 0, stream>>>(q_hidden, c_hidden, q_mask, c_mask,
                                        Wt, bias, qcolP, ccol);
  sim_kernel<<<dim3(64, 8), 128, 0, stream>>>(qcolP, ccol, q_mask, sim);
}

// Round 4
// 374.675 us; speedup vs baseline: 1.1436x; 1.1436x over previous
//
#include <hip/hip_runtime.h>
#include <hip/hip_bf16.h>

// Shapes (fixed by the reference)
#define QN 64
#define SQ 32
#define CN 256
#define SC 256
#define HD 768
#define DD 128

typedef __attribute__((ext_vector_type(8))) short short8;   // 8 bf16 = 4 VGPR
typedef __attribute__((ext_vector_type(4))) float f32x4;    // MFMA acc

// ---- bf16 pack helpers (RNE) ----
static __device__ __forceinline__ unsigned short f2bf(float x) {
  unsigned u = __float_as_uint(x);
  unsigned r = 0x7FFFu + ((u >> 16) & 1u);
  return (unsigned short)((u + r) >> 16);
}
static __device__ __forceinline__ unsigned pack2(float a, float b) {
  return (unsigned)f2bf(a) | ((unsigned)f2bf(b) << 16);
}

// ---- async global->LDS, 16B per lane; LDS dest = wave-uniform base + lane*16
typedef const __attribute__((address_space(1))) unsigned int* as1_u32p;
typedef __attribute__((address_space(3))) unsigned int* as3_u32p;
static __device__ __forceinline__ void gl_lds16(const void* g, void* l) {
  __builtin_amdgcn_global_load_lds((as1_u32p)g, (as3_u32p)l, 16, 0, 0);
}

// ---------------------------------------------------------------------------
// Prep (fused):
//  blocks [0,128):  WtS[d][kc'] = bf16(W[k][d]) in 16B chunks, chunk-XOR
//                   swizzled: kc' = (kc & ~7) | ((kc&7) ^ (d&7)), kc = k/8.
//  blocks [128,448): pooled l2norm rows (64 q + 256 c); q rows also zero
//                   qcolP pad row 31.
// ---------------------------------------------------------------------------
__global__ __launch_bounds__(256) void prep_kernel(
    const float* __restrict__ W,
    const float* __restrict__ qh, const int* __restrict__ qm,
    const float* __restrict__ ch, const int* __restrict__ cm,
    unsigned short* __restrict__ WtS,
    float* __restrict__ outq, float* __restrict__ outc,
    unsigned short* __restrict__ qcolP) {
  __shared__ float red[4];
  int bid = blockIdx.x, tid = threadIdx.x;

  if (bid < DD) {  // W transpose-convert, swizzled chunks
    int d = bid;
    if (tid < 96) {
      int kc = tid;
      unsigned p[4];
#pragma unroll
      for (int e = 0; e < 4; ++e) {
        float a = W[(size_t)(kc * 8 + 2 * e) * DD + d];
        float b = W[(size_t)(kc * 8 + 2 * e + 1) * DD + d];
        p[e] = pack2(a, b);
      }
      int kcp = (kc & ~7) | ((kc & 7) ^ (d & 7));
      *(uint4*)&WtS[((size_t)d * 96 + kcp) * 8] = *(uint4*)p;
    }
    return;
  }

  int row = bid - DD;
  const float* src;
  float* dst;
  float m;
  if (row < QN) {
    src = qh + (size_t)row * SQ * HD;
    m = (float)qm[row * SQ];
    dst = outq + (size_t)row * HD;
  } else {
    int b = row - QN;
    src = ch + (size_t)b * SC * HD;
    m = (float)cm[b * SC];
    dst = outc + (size_t)b * HD;
  }
  float ss = 0.f;
  for (int k = tid; k < HD; k += 256) {
    float v = src[k] * m;
    ss += v * v;
  }
  int lane = tid & 63, wv = tid >> 6;
  for (int off = 32; off; off >>= 1) ss += __shfl_xor(ss, off);
  if (lane == 0) red[wv] = ss;
  __syncthreads();
  float tot = red[0] + red[1] + red[2] + red[3];
  float inv = 1.f / fmaxf(sqrtf(tot), 1e-12f);
  for (int k = tid; k < HD; k += 256) dst[k] = src[k] * m * inv;
  if (row < QN && tid < 64)
    ((unsigned*)(qcolP + ((size_t)row * 32 + 31) * DD))[tid] = 0u;
}

// ---------------------------------------------------------------------------
// Projection GEMM (MFMA): col = l2norm(m*(h@W) + b)
//  Blocks [0,510): c tokens (128/block).  Blocks [510,526): q tokens.
//  A (tokens) loaded global->VGPR per k-window (no LDS: zero cross-wave
//  reuse); W staged in LDS via global_load_lds in 3 x 64KB K-slices.
//  Mask applied in epilogue (exact: (h*m)@W + b == m*(h@W) + b).
//  Stores bf16: q linear [q][32][128]; c chunk-swizzled within each row:
//  chunk pos = (kc&8) | ((kc&7) ^ (tok&7))  (matches sim's LDS read pattern).
// ---------------------------------------------------------------------------
union ProjLDS {
  unsigned short b[128 * 32 * 8];  // 64 KB: 128 d-rows x 32 chunks (K-slice)
  float cep[128 * 132];            // 67.6 KB epilogue C tile
};

__global__ __launch_bounds__(256, 2) void proj_kernel(
    const float* __restrict__ q_hidden, const float* __restrict__ c_hidden,
    const int* __restrict__ q_mask, const int* __restrict__ c_mask,
    const unsigned short* __restrict__ WtS, const float* __restrict__ bias,
    unsigned short* __restrict__ qcol, unsigned short* __restrict__ ccol) {
  __shared__ ProjLDS u;
  int bx = blockIdx.x;
  int isQ = (bx >= 510) ? 1 : 0;
  int base = isQ ? (bx - 510) : bx;
  int tid = threadIdx.x, lane = tid & 63, wv = tid >> 6;
  int lm = lane & 15, lq = lane >> 4;

  // ---- A row pointers for this wave's 2 m-tiles (token = wv*32+mt*16+lm) ----
  const float* hrow[2];
#pragma unroll
  for (int mt = 0; mt < 2; ++mt) {
    int g = base * 128 + wv * 32 + mt * 16 + lm;
    const float* hp;
    if (isQ) {
      g = (g < 1983) ? g : 1983;
      int qq = g / 31, t = g - qq * 31;
      hp = q_hidden + ((size_t)qq * SQ + t + 1) * HD;
    } else {
      int cb = g / 255, t = g - cb * 255;
      hp = c_hidden + ((size_t)cb * SC + t + 1) * HD;
    }
    hrow[mt] = hp;
  }

  f32x4 acc[2][8];
#pragma unroll
  for (int i = 0; i < 2; ++i)
#pragma unroll
    for (int j = 0; j < 8; ++j) acc[i][j] = (f32x4){0.f, 0.f, 0.f, 0.f};

  for (int stage = 0; stage < 3; ++stage) {
    __syncthreads();
    // ---- stage W K-slice: 128 d x 32 chunks = 64 KB, async, linear ----
#pragma unroll
    for (int i = 0; i < 16; ++i) {
      int d = i * 8 + wv * 2 + (lane >> 5);
      int lc = lane & 31;
      gl_lds16(WtS + ((size_t)d * 96 + stage * 32 + lc) * 8,
               (char*)u.b + (size_t)(i * 256 + wv * 64) * 16);
    }
    __syncthreads();

#pragma unroll
    for (int w = 0; w < 8; ++w) {  // 8 k-windows of 32 per stage
      int kwin = stage * 8 + w;
      // A frags: global f32 -> bf16 regs
      short8 afr[2];
#pragma unroll
      for (int mt = 0; mt < 2; ++mt) {
        const float* ha = hrow[mt] + kwin * 32 + lq * 8;
        float4 a0 = *(const float4*)ha;
        float4 a1 = *(const float4*)(ha + 4);
        unsigned p[4];
        p[0] = pack2(a0.x, a0.y); p[1] = pack2(a0.z, a0.w);
        p[2] = pack2(a1.x, a1.y); p[3] = pack2(a1.z, a1.w);
        afr[mt] = *(short8*)p;
      }
      // B frags from LDS (conflict-free via swizzle)
      int t = w * 4 + lq;
      int lcp = (t & ~7) | ((t & 7) ^ (lm & 7));
      short8 bfr[8];
#pragma unroll
      for (int nt = 0; nt < 8; ++nt) {
        int ci = (nt * 16 + lm) * 32 + lcp;
        bfr[nt] = *(const short8*)&u.b[(size_t)ci * 8];
      }
#pragma unroll
      for (int mt = 0; mt < 2; ++mt)
#pragma unroll
        for (int nt = 0; nt < 8; ++nt)
          acc[mt][nt] = __builtin_amdgcn_mfma_f32_16x16x32_bf16(afr[mt], bfr[nt], acc[mt][nt], 0, 0, 0);
    }
  }

  // ---- epilogue: C tile -> LDS, mask + bias + l2norm, bf16 store ----
  __syncthreads();
#pragma unroll
  for (int mt = 0; mt < 2; ++mt)
#pragma unroll
    for (int nt = 0; nt < 8; ++nt)
#pragma unroll
      for (int r = 0; r < 4; ++r) {
        int rw = wv * 32 + mt * 16 + lq * 4 + r;
        int col = nt * 16 + lm;
        u.cep[rw * 132 + col] = acc[mt][nt][r];
      }
  __syncthreads();

  int tk = tid >> 1, hf = tid & 1;     // token-local, d-half
  int g = base * 128 + tk;
  int qq, t, valid = 1;
  float fm;
  if (isQ) {
    if (g >= 1983) { valid = (g == 1983); g = 1983; }
    qq = g / 31; t = g - qq * 31;
    fm = (float)q_mask[qq * SQ + t + 1];
  } else {
    qq = g / 255; t = g - qq * 255;
    fm = (float)c_mask[qq * SC + t + 1];
  }

  float v[64];
  float ss = 0.f;
#pragma unroll
  for (int j = 0; j < 16; ++j) {
    float4 cv = *(const float4*)&u.cep[tk * 132 + hf * 64 + j * 4];
    float4 bv = *(const float4*)&bias[hf * 64 + j * 4];
    v[4 * j + 0] = cv.x * fm + bv.x; v[4 * j + 1] = cv.y * fm + bv.y;
    v[4 * j + 2] = cv.z * fm + bv.z; v[4 * j + 3] = cv.w * fm + bv.w;
#pragma unroll
    for (int e = 0; e < 4; ++e) ss += v[4 * j + e] * v[4 * j + e];
  }
  ss += __shfl_xor(ss, 1);
  float inv = 1.f / fmaxf(sqrtf(ss), 1e-12f);

  uint4 pk4[8];
#pragma unroll
  for (int j = 0; j < 8; ++j) {
    unsigned p[4];
#pragma unroll
    for (int e = 0; e < 4; ++e)
      p[e] = pack2(v[8 * j + 2 * e] * inv, v[8 * j + 2 * e + 1] * inv);
    pk4[j] = *(uint4*)p;
  }

  if (isQ) {
    if (valid) {
      uint4* dst = (uint4*)(qcol + ((size_t)qq * 32 + t) * DD + hf * 64);
#pragma unroll
      for (int j = 0; j < 8; ++j) dst[j] = pk4[j];
    }
  } else {
    uint4* rowp = (uint4*)(ccol + ((size_t)qq * 256 + t) * DD);
#pragma unroll
    for (int j = 0; j < 8; ++j) {
      int kc = hf * 8 + j;
      int p = (kc & 8) | ((kc & 7) ^ (t & 7));
      rowp[p] = pk4[j];
    }
    if (t == 254) {  // duplicate into pad row 255 (row&7 = 7)
      uint4* rowp2 = rowp + 8;  // +128 shorts = +8 uint4
#pragma unroll
      for (int j = 0; j < 8; ++j) {
        int kc = hf * 8 + j;
        int p = (kc & 8) | ((kc & 7) ^ 7);
        rowp2[p] = pk4[j];
      }
    }
  }
}

// ---------------------------------------------------------------------------
// Sim (MFMA): sim[q,c] = (sum_i max_j qcol[q,i]·ccol[c,j]) / denom[q]
// Grid (64, 8), 256 thr = 4 waves, 2 blocks/CU. Each wave: 2 q (B-side regs).
// c-tile (256x128 bf16 = 64 KB) staged LINEARLY via global_load_lds — ccol is
// already chunk-swizzled by proj, so LDS frag reads are conflict-free.
// ---------------------------------------------------------------------------
__global__ __launch_bounds__(256, 2) void sim_kernel(
    const unsigned short* __restrict__ qcolP,  // [64][32][128], row 31 zero
    const unsigned short* __restrict__ ccol,   // swizzled, row 255 dup
    const int* __restrict__ qmask,
    float* __restrict__ sim) {
  __shared__ unsigned short cbuf[256 * 128];   // 64 KB
  int tid = threadIdx.x, lane = tid & 63, wv = tid >> 6;
  int lm = lane & 15, lq = lane >> 4;
  int qb = blockIdx.y * 8 + wv * 2;  // 2 q per wave
  int c0 = blockIdx.x * 4;

  // B fragments (q side): af[q2][it][kf]
  short8 af[2][2][4];
#pragma unroll
  for (int q2 = 0; q2 < 2; ++q2)
#pragma unroll
    for (int it = 0; it < 2; ++it)
#pragma unroll
      for (int kf = 0; kf < 4; ++kf)
        af[q2][it][kf] = *(const short8*)(qcolP +
            (((size_t)(qb + q2) * 32 + it * 16 + lm) * DD + kf * 32 + lq * 8));

  float dinv[2];
#pragma unroll
  for (int q2 = 0; q2 < 2; ++q2) {
    float v = (lane >= 1 && lane < 32) ? (float)qmask[(qb + q2) * SQ + lane] : 0.f;
    for (int off = 1; off < 64; off <<= 1) v += __shfl_xor(v, off);
    dinv[q2] = 1.f / v;
  }

  for (int cc = 0; cc < 4; ++cc) {
    int c = c0 + cc;
    __syncthreads();
    // ---- linear async copy of the pre-swizzled c-tile ----
    const unsigned short* src = ccol + (size_t)c * SC * DD;
#pragma unroll
    for (int i = 0; i < 16; ++i) {
      gl_lds16(src + (size_t)(i * 256 + wv * 64 + lane) * 8,
               (char*)cbuf + (size_t)(i * 256 + wv * 64) * 16);
    }
    __syncthreads();

    float rmax[2][2];
#pragma unroll
    for (int q2 = 0; q2 < 2; ++q2) { rmax[q2][0] = -__builtin_inff(); rmax[q2][1] = -__builtin_inff(); }

    for (int jt = 0; jt < 16; ++jt) {
      short8 cf[4];  // A operand: c rows jt*16+lm
#pragma unroll
      for (int kf = 0; kf < 4; ++kf) {
        int row = jt * 16 + lm;
        int kc = kf * 4 + lq;
        int p = (kc & 8) | ((kc & 7) ^ (row & 7));
        cf[kf] = *(const short8*)&cbuf[(size_t)(row * 16 + p) * 8];
      }
#pragma unroll
      for (int q2 = 0; q2 < 2; ++q2)
#pragma unroll
        for (int it = 0; it < 2; ++it) {
          f32x4 acc = (f32x4){0.f, 0.f, 0.f, 0.f};
#pragma unroll
          for (int kf = 0; kf < 4; ++kf)
            acc = __builtin_amdgcn_mfma_f32_16x16x32_bf16(cf[kf], af[q2][it][kf], acc, 0, 0, 0);
          float loc = fmaxf(fmaxf(acc[0], acc[1]), fmaxf(acc[2], acc[3]));
          rmax[q2][it] = fmaxf(rmax[q2][it], loc);
        }
    }

#pragma unroll
    for (int q2 = 0; q2 < 2; ++q2) {
      float m0 = rmax[q2][0], m1 = rmax[q2][1];
      m0 = fmaxf(m0, __shfl_xor(m0, 16)); m0 = fmaxf(m0, __shfl_xor(m0, 32));
      m1 = fmaxf(m1, __shfl_xor(m1, 16)); m1 = fmaxf(m1, __shfl_xor(m1, 32));
      // q-row i = lm (+16 for it=1); pad row 31 = (it=1, lm=15) excluded
      float s = m0 + ((lm == 15) ? 0.f : m1);
      s += __shfl_xor(s, 1); s += __shfl_xor(s, 2);
      s += __shfl_xor(s, 4); s += __shfl_xor(s, 8);
      if (lane == 0) sim[(qb + q2) * CN + c] = s * dinv[q2];
    }
  }
}

// ---------------------------------------------------------------------------
extern "C" void kernel_launch(void* const* d_in, const int* in_sizes, int n_in,
                              void* d_out, int out_size, void* d_ws, size_t ws_size,
                              hipStream_t stream) {
  const float* q_hidden = (const float*)d_in[0];
  const float* c_hidden = (const float*)d_in[1];
  const float* W = (const float*)d_in[2];
  const float* bias = (const float*)d_in[3];
  const int* q_mask = (const int*)d_in[4];
  const int* c_mask = (const int*)d_in[5];

  float* out = (float*)d_out;
  float* sim = out;                      // 64*256
  float* q_pooled = out + QN * CN;       // 64*768
  float* c_pooled = q_pooled + QN * HD;  // 256*768

  unsigned short* WtS   = (unsigned short*)d_ws;                        // 192 KB
  unsigned short* qcolP = (unsigned short*)((char*)d_ws + (256 << 10)); // 512 KB
  unsigned short* ccol  = (unsigned short*)((char*)d_ws + (1 << 20));   // 16 MB

  prep_kernel<<<DD + QN + CN, 256, 0, stream>>>(W, q_hidden, q_mask, c_hidden, c_mask,
                                                WtS, q_pooled, c_pooled, qcolP);
  proj_kernel<<<526, 256, 0, stream>>>(q_hidden, c_hidden, q_mask, c_mask,
                                       WtS, bias, qcolP, ccol);
  sim_kernel<<<dim3(64, 8), 256, 0, stream>>>(qcolP, ccol, q_mask, sim);
}

// Round 5
// 363.748 us; speedup vs baseline: 1.1779x; 1.0300x over previous
//
#include <hip/hip_runtime.h>
#include <hip/hip_bf16.h>

// Shapes (fixed by the reference)
#define QN 64
#define SQ 32
#define CN 256
#define SC 256
#define HD 768
#define DD 128

typedef __attribute__((ext_vector_type(8))) short short8;   // 8 bf16 = 4 VGPR
typedef __attribute__((ext_vector_type(4))) float f32x4;    // MFMA acc

// ---- bf16 pack helpers (RNE) ----
static __device__ __forceinline__ unsigned short f2bf(float x) {
  unsigned u = __float_as_uint(x);
  unsigned r = 0x7FFFu + ((u >> 16) & 1u);
  return (unsigned short)((u + r) >> 16);
}
static __device__ __forceinline__ unsigned pack2(float a, float b) {
  return (unsigned)f2bf(a) | ((unsigned)f2bf(b) << 16);
}

// ---- async global->LDS, 16B/lane; LDS dest = wave-uniform base + lane*16 ----
typedef const __attribute__((address_space(1))) unsigned int* as1_u32p;
typedef __attribute__((address_space(3))) unsigned int* as3_u32p;
static __device__ __forceinline__ void gl_lds16(const void* g, void* l) {
  __builtin_amdgcn_global_load_lds((as1_u32p)g, (as3_u32p)l, 16, 0, 0);
}

// ---------------------------------------------------------------------------
// Prep (fused):
//  blocks [0,128):  WtS[d][kc'] = bf16(W[k][d]) in 16B chunks (8 bf16), XOR
//                   swizzled within 8-chunk groups: kc' = (kc&~7)|((kc&7)^(d&7)).
//  blocks [128,448): pooled l2norm rows (64 q + 256 c); q rows also zero
//                   qcolP pad row 31.
// ---------------------------------------------------------------------------
__global__ __launch_bounds__(256) void prep_kernel(
    const float* __restrict__ W,
    const float* __restrict__ qh, const int* __restrict__ qm,
    const float* __restrict__ ch, const int* __restrict__ cm,
    unsigned short* __restrict__ WtS,
    float* __restrict__ outq, float* __restrict__ outc,
    unsigned short* __restrict__ qcolP) {
  __shared__ float red[4];
  int bid = blockIdx.x, tid = threadIdx.x;

  if (bid < DD) {  // W transpose-convert, swizzled chunks
    int d = bid;
    if (tid < 96) {
      int kc = tid;
      unsigned p[4];
#pragma unroll
      for (int e = 0; e < 4; ++e) {
        float a = W[(size_t)(kc * 8 + 2 * e) * DD + d];
        float b = W[(size_t)(kc * 8 + 2 * e + 1) * DD + d];
        p[e] = pack2(a, b);
      }
      int kcp = (kc & ~7) | ((kc & 7) ^ (d & 7));
      *(uint4*)&WtS[((size_t)d * 96 + kcp) * 8] = *(uint4*)p;
    }
    return;
  }

  int row = bid - DD;
  const float* src;
  float* dst;
  float m;
  if (row < QN) {
    src = qh + (size_t)row * SQ * HD;
    m = (float)qm[row * SQ];
    dst = outq + (size_t)row * HD;
  } else {
    int b = row - QN;
    src = ch + (size_t)b * SC * HD;
    m = (float)cm[b * SC];
    dst = outc + (size_t)b * HD;
  }
  float ss = 0.f;
  for (int k = tid; k < HD; k += 256) {
    float v = src[k] * m;
    ss += v * v;
  }
  int lane = tid & 63, wv = tid >> 6;
  for (int off = 32; off; off >>= 1) ss += __shfl_xor(ss, off);
  if (lane == 0) red[wv] = ss;
  __syncthreads();
  float tot = red[0] + red[1] + red[2] + red[3];
  float inv = 1.f / fmaxf(sqrtf(tot), 1e-12f);
  for (int k = tid; k < HD; k += 256) dst[k] = src[k] * m * inv;
  if (row < QN && tid < 64)
    ((unsigned*)(qcolP + ((size_t)row * 32 + 31) * DD))[tid] = 0u;
}

// ---------------------------------------------------------------------------
// Projection GEMM (MFMA): col = l2norm(m*(h@W) + b)
//  Blocks [0,510): c tokens (128/block).  Blocks [510,526): q tokens.
//  BOTH A (f32 h rows) and W staged via global_load_lds, BK=64, 12 k-steps.
//  A's LDS image is chunk-XOR-swizzled by swizzling the GLOBAL source address
//  per lane (linear-dest constraint); W source (WtS) is pre-swizzled.
//  Mask applied in epilogue (exact: (h*m)@W + b == m*(h@W) + b).
//  Epilogue in two 64-row halves reusing the staging LDS (48 KB total).
// ---------------------------------------------------------------------------
union ProjLDS {
  struct { float a[128 * 64]; unsigned short w[128 * 64]; } s;  // 32 KB + 16 KB
  float cep[64 * 132];                                          // 33.8 KB
};

__global__ __launch_bounds__(256, 3) void proj_kernel(
    const float* __restrict__ q_hidden, const float* __restrict__ c_hidden,
    const int* __restrict__ q_mask, const int* __restrict__ c_mask,
    const unsigned short* __restrict__ WtS, const float* __restrict__ bias,
    unsigned short* __restrict__ qcol, unsigned short* __restrict__ ccol) {
  __shared__ ProjLDS u;
  int bx = blockIdx.x;
  int isQ = (bx >= 510) ? 1 : 0;
  int base = isQ ? (bx - 510) : bx;
  int tid = threadIdx.x, lane = tid & 63, wv = tid >> 6;
  int lm = lane & 15, lq = lane >> 4;

  // ---- A staging sources: 8 slots/thread, slot = i*256+tid ----
  // row r = i*16 + (tid>>4); phys chunk p = tid&15; logical c = (p&8)|((p&7)^(r&7))
  int ac = (tid & 8) | ((tid & 7) ^ ((tid >> 4) & 7));
  const float* aptr[8];
#pragma unroll
  for (int i = 0; i < 8; ++i) {
    int r = i * 16 + (tid >> 4);
    int g = base * 128 + r;
    const float* hp;
    if (isQ) {
      g = (g < 1983) ? g : 1983;
      int qq = g / 31, t = g - qq * 31;
      hp = q_hidden + ((size_t)qq * SQ + t + 1) * HD;
    } else {
      int cb = g / 255, t = g - cb * 255;
      hp = c_hidden + ((size_t)cb * SC + t + 1) * HD;
    }
    aptr[i] = hp + ac * 4;
  }
  // ---- W staging sources: 4 slots/thread, slot = i*256+tid (linear copy) ----
  const unsigned short* wptr[4];
#pragma unroll
  for (int i = 0; i < 4; ++i) {
    int d = i * 32 + (tid >> 3);
    wptr[i] = WtS + ((size_t)d * 96 + (tid & 7)) * 8;
  }

  f32x4 acc[2][8];
#pragma unroll
  for (int i = 0; i < 2; ++i)
#pragma unroll
    for (int j = 0; j < 8; ++j) acc[i][j] = (f32x4){0.f, 0.f, 0.f, 0.f};

  for (int step = 0; step < 12; ++step) {
    __syncthreads();
#pragma unroll
    for (int i = 0; i < 8; ++i)
      gl_lds16(aptr[i] + step * 64, (char*)u.s.a + (size_t)(i * 256 + wv * 64) * 16);
#pragma unroll
    for (int i = 0; i < 4; ++i)
      gl_lds16(wptr[i] + step * 64, (char*)u.s.w + (size_t)(i * 256 + wv * 64) * 16);
    __syncthreads();

#pragma unroll
    for (int w = 0; w < 2; ++w) {  // 2 k-windows of 32 per step
      short8 afr[2];
#pragma unroll
      for (int mt = 0; mt < 2; ++mt) {
        int rr = wv * 32 + mt * 16 + lm;
        int x0 = (lq * 2) ^ (lm & 7);
        int x1 = (lq * 2 + 1) ^ (lm & 7);
        float4 a0 = *(const float4*)&u.s.a[rr * 64 + w * 32 + x0 * 4];
        float4 a1 = *(const float4*)&u.s.a[rr * 64 + w * 32 + x1 * 4];
        unsigned p[4];
        p[0] = pack2(a0.x, a0.y); p[1] = pack2(a0.z, a0.w);
        p[2] = pack2(a1.x, a1.y); p[3] = pack2(a1.z, a1.w);
        afr[mt] = *(short8*)p;
      }
      short8 bfr[8];
#pragma unroll
      for (int nt = 0; nt < 8; ++nt) {
        int d = nt * 16 + lm;
        int pc = (w * 4 + lq) ^ (lm & 7);
        bfr[nt] = *(const short8*)&u.s.w[d * 64 + pc * 8];
      }
#pragma unroll
      for (int mt = 0; mt < 2; ++mt)
#pragma unroll
        for (int nt = 0; nt < 8; ++nt)
          acc[mt][nt] = __builtin_amdgcn_mfma_f32_16x16x32_bf16(afr[mt], bfr[nt], acc[mt][nt], 0, 0, 0);
    }
  }

  // ---- epilogue: two 64-row halves through LDS ----
  int tk = tid >> 2, qt = tid & 3;  // row-in-half, 32-d quarter
#pragma unroll
  for (int h = 0; h < 2; ++h) {
    __syncthreads();
    if ((wv >> 1) == h) {
#pragma unroll
      for (int mt = 0; mt < 2; ++mt)
#pragma unroll
        for (int nt = 0; nt < 8; ++nt)
#pragma unroll
          for (int r = 0; r < 4; ++r) {
            int row = (wv & 1) * 32 + mt * 16 + lq * 4 + r;
            u.cep[row * 132 + nt * 16 + lm] = acc[mt][nt][r];
          }
    }
    __syncthreads();

    int g = base * 128 + h * 64 + tk;
    int qq, t, valid = 1;
    float fm;
    if (isQ) {
      if (g > 1983) { valid = 0; g = 1983; }
      qq = g / 31; t = g - qq * 31;
      fm = (float)q_mask[qq * SQ + t + 1];
    } else {
      qq = g / 255; t = g - qq * 255;
      fm = (float)c_mask[qq * SC + t + 1];
    }

    float v[32];
    float ss = 0.f;
#pragma unroll
    for (int j = 0; j < 8; ++j) {
      float4 cv = *(const float4*)&u.cep[tk * 132 + qt * 32 + j * 4];
      float4 bv = *(const float4*)&bias[qt * 32 + j * 4];
      v[4 * j + 0] = cv.x * fm + bv.x; v[4 * j + 1] = cv.y * fm + bv.y;
      v[4 * j + 2] = cv.z * fm + bv.z; v[4 * j + 3] = cv.w * fm + bv.w;
#pragma unroll
      for (int e = 0; e < 4; ++e) ss += v[4 * j + e] * v[4 * j + e];
    }
    ss += __shfl_xor(ss, 1);
    ss += __shfl_xor(ss, 2);
    float inv = 1.f / fmaxf(sqrtf(ss), 1e-12f);

    uint4 pk4[4];
#pragma unroll
    for (int j = 0; j < 4; ++j) {
      unsigned p[4];
#pragma unroll
      for (int e = 0; e < 4; ++e)
        p[e] = pack2(v[8 * j + 2 * e] * inv, v[8 * j + 2 * e + 1] * inv);
      pk4[j] = *(uint4*)p;
    }

    if (isQ) {
      if (valid) {
        uint4* dst = (uint4*)(qcol + ((size_t)qq * 32 + t) * DD + qt * 32);
#pragma unroll
        for (int j = 0; j < 4; ++j) dst[j] = pk4[j];
      }
    } else {
      uint4* rowp = (uint4*)(ccol + ((size_t)qq * 256 + t) * DD);
#pragma unroll
      for (int j = 0; j < 4; ++j) {
        int kc = qt * 4 + j;
        int p = (kc & 8) | ((kc & 7) ^ (t & 7));
        rowp[p] = pk4[j];
      }
      if (t == 254) {  // duplicate into pad row 255 (row&7 = 7)
        uint4* rowp2 = rowp + 8;
#pragma unroll
        for (int j = 0; j < 4; ++j) {
          int kc = qt * 4 + j;
          int p = (kc & 8) | ((kc & 7) ^ 7);
          rowp2[p] = pk4[j];
        }
      }
    }
  }
}

// ---------------------------------------------------------------------------
// Sim (MFMA): sim[q,c] = (sum_i max_j qcol[q,i]·ccol[c,j]) / denom[q]
// Grid (128, 4), 256 thr = 4 waves, 2 blocks/CU. 4 q per wave (16 q/block),
// 2 c-tiles looped per block. c-tile (64 KB) staged linearly via
// global_load_lds — ccol is pre-swizzled by proj, frag reads conflict-free.
// ---------------------------------------------------------------------------
__global__ __launch_bounds__(256, 2) void sim_kernel(
    const unsigned short* __restrict__ qcolP,  // [64][32][128], row 31 zero
    const unsigned short* __restrict__ ccol,   // swizzled, row 255 dup
    const int* __restrict__ qmask,
    float* __restrict__ sim) {
  __shared__ unsigned short cbuf[256 * 128];   // 64 KB
  int tid = threadIdx.x, lane = tid & 63, wv = tid >> 6;
  int lm = lane & 15, lq = lane >> 4;
  int qb = blockIdx.y * 16 + wv * 4;  // 4 q per wave
  int c0 = blockIdx.x * 2;

  // B fragments (q side): af[q2][it][kf]
  short8 af[4][2][4];
#pragma unroll
  for (int q2 = 0; q2 < 4; ++q2)
#pragma unroll
    for (int it = 0; it < 2; ++it)
#pragma unroll
      for (int kf = 0; kf < 4; ++kf)
        af[q2][it][kf] = *(const short8*)(qcolP +
            (((size_t)(qb + q2) * 32 + it * 16 + lm) * DD + kf * 32 + lq * 8));

  float dinv[4];
#pragma unroll
  for (int q2 = 0; q2 < 4; ++q2) {
    float v = (lane >= 1 && lane < 32) ? (float)qmask[(qb + q2) * SQ + lane] : 0.f;
    for (int off = 1; off < 64; off <<= 1) v += __shfl_xor(v, off);
    dinv[q2] = 1.f / v;
  }

  for (int cc = 0; cc < 2; ++cc) {
    int c = c0 + cc;
    __syncthreads();
    const unsigned short* src = ccol + (size_t)c * SC * DD;
#pragma unroll
    for (int i = 0; i < 16; ++i)
      gl_lds16(src + (size_t)(i * 256 + wv * 64 + lane) * 8,
               (char*)cbuf + (size_t)(i * 256 + wv * 64) * 16);
    __syncthreads();

    float rmax[4][2];
#pragma unroll
    for (int q2 = 0; q2 < 4; ++q2) { rmax[q2][0] = -__builtin_inff(); rmax[q2][1] = -__builtin_inff(); }

    for (int jt = 0; jt < 16; ++jt) {
      short8 cf[4];  // A operand: c rows jt*16+lm
#pragma unroll
      for (int kf = 0; kf < 4; ++kf) {
        int row = jt * 16 + lm;
        int kc = kf * 4 + lq;
        int p = (kc & 8) | ((kc & 7) ^ (row & 7));
        cf[kf] = *(const short8*)&cbuf[(size_t)(row * 16 + p) * 8];
      }
#pragma unroll
      for (int q2 = 0; q2 < 4; ++q2)
#pragma unroll
        for (int it = 0; it < 2; ++it) {
          f32x4 acc = (f32x4){0.f, 0.f, 0.f, 0.f};
#pragma unroll
          for (int kf = 0; kf < 4; ++kf)
            acc = __builtin_amdgcn_mfma_f32_16x16x32_bf16(cf[kf], af[q2][it][kf], acc, 0, 0, 0);
          float loc = fmaxf(fmaxf(acc[0], acc[1]), fmaxf(acc[2], acc[3]));
          rmax[q2][it] = fmaxf(rmax[q2][it], loc);
        }
    }

#pragma unroll
    for (int q2 = 0; q2 < 4; ++q2) {
      float m0 = rmax[q2][0], m1 = rmax[q2][1];
      m0 = fmaxf(m0, __shfl_xor(m0, 16)); m0 = fmaxf(m0, __shfl_xor(m0, 32));
      m1 = fmaxf(m1, __shfl_xor(m1, 16)); m1 = fmaxf(m1, __shfl_xor(m1, 32));
      // q-row i = lm (+16 for it=1); pad row 31 = (it=1, lm=15) excluded
      float s = m0 + ((lm == 15) ? 0.f : m1);
      s += __shfl_xor(s, 1); s += __shfl_xor(s, 2);
      s += __shfl_xor(s, 4); s += __shfl_xor(s, 8);
      if (lane == 0) sim[(qb + q2) * CN + c] = s * dinv[q2];
    }
  }
}

// ---------------------------------------------------------------------------
extern "C" void kernel_launch(void* const* d_in, const int* in_sizes, int n_in,
                              void* d_out, int out_size, void* d_ws, size_t ws_size,
                              hipStream_t stream) {
  const float* q_hidden = (const float*)d_in[0];
  const float* c_hidden = (const float*)d_in[1];
  const float* W = (const float*)d_in[2];
  const float* bias = (const float*)d_in[3];
  const int* q_mask = (const int*)d_in[4];
  const int* c_mask = (const int*)d_in[5];

  float* out = (float*)d_out;
  float* sim = out;                      // 64*256
  float* q_pooled = out + QN * CN;       // 64*768
  float* c_pooled = q_pooled + QN * HD;  // 256*768

  unsigned short* WtS   = (unsigned short*)d_ws;                        // 192 KB
  unsigned short* qcolP = (unsigned short*)((char*)d_ws + (256 << 10)); // 512 KB
  unsigned short* ccol  = (unsigned short*)((char*)d_ws + (1 << 20));   // 16 MB

  prep_kernel<<<DD + QN + CN, 256, 0, stream>>>(W, q_hidden, q_mask, c_hidden, c_mask,
                                                WtS, q_pooled, c_pooled, qcolP);
  proj_kernel<<<526, 256, 0, stream>>>(q_hidden, c_hidden, q_mask, c_mask,
                                       WtS, bias, qcolP, ccol);
  sim_kernel<<<dim3(128, 4), 256, 0, stream>>>(qcolP, ccol, q_mask, sim);
}